// Round 1
// baseline (213.902 us; speedup 1.0000x reference)
//
#include <hip/hip_runtime.h>

// Problem constants
constexpr int   TILE   = 2048;          // outputs per block
constexpr int   PADZ   = 375;           // 125 (MA halo) + 250 (MV halo)
constexpr int   PADY   = 250;
constexpr int   TOTZ   = TILE + 2*PADZ; // 2798 z-values needed per block
constexpr int   TOTY   = TILE + 2*PADY; // 2548 y-values needed per block
constexpr int   PT     = 11;            // elems per thread in the scan (11 coprime to 32 banks)
constexpr int   SCAN_LEN = 256 * PT;    // 2816 >= TOTZ >= TOTY
constexpr float EPS    = 1e-5f;

// ---------------------------------------------------------------------------
// Kernel 1: global sum / sum-of-squares reduction (double accumulation)
// ---------------------------------------------------------------------------
__global__ __launch_bounds__(256) void reduce_kernel(const float* __restrict__ x,
                                                     long long n, double* ws) {
    int tid = threadIdx.x;
    size_t gid    = (size_t)blockIdx.x * blockDim.x + tid;
    size_t stride = (size_t)gridDim.x * blockDim.x;
    double s = 0.0, s2 = 0.0;
    const float4* x4 = (const float4*)x;
    size_t n4 = (size_t)(n >> 2);
    for (size_t i = gid; i < n4; i += stride) {
        float4 v = x4[i];
        s  += (double)v.x + (double)v.y + (double)v.z + (double)v.w;
        s2 += (double)v.x * v.x + (double)v.y * v.y +
              (double)v.z * v.z + (double)v.w * v.w;
    }
    // wave64 reduction
    for (int off = 32; off; off >>= 1) {
        s  += __shfl_down(s, off);
        s2 += __shfl_down(s2, off);
    }
    __shared__ double ls[4], ls2[4];
    int wid = tid >> 6, lane = tid & 63;
    if (lane == 0) { ls[wid] = s; ls2[wid] = s2; }
    __syncthreads();
    if (tid == 0) {
        double a = 0.0, b = 0.0;
        for (int w = 0; w < 4; ++w) { a += ls[w]; b += ls2[w]; }
        atomicAdd(&ws[0], a);
        atomicAdd(&ws[1], b);
    }
}

// ---------------------------------------------------------------------------
// Block-local inclusive scan over a SCAN_LEN float array in LDS.
// Per-thread sequential chunk (stride PT=11 -> bank-conflict-free), then
// Hillis-Steele across the 256 thread totals.
// ---------------------------------------------------------------------------
__device__ inline void scan_inplace(float* a, float* tsum, int tid) {
    int base = tid * PT;
    float run = 0.f;
    #pragma unroll
    for (int k = 0; k < PT; ++k) { run += a[base + k]; a[base + k] = run; }
    tsum[tid] = run;
    __syncthreads();
    #pragma unroll
    for (int off = 1; off < 256; off <<= 1) {
        float v = (tid >= off) ? tsum[tid - off] : 0.f;
        __syncthreads();
        tsum[tid] += v;
        __syncthreads();
    }
    float add = (tid > 0) ? tsum[tid - 1] : 0.f;
    #pragma unroll
    for (int k = 0; k < PT; ++k) a[base + k] += add;
    __syncthreads();
}

// ---------------------------------------------------------------------------
// Kernel 2: fused z-score -> (z - MA251(z)) -> / (sqrt(MA501(y^2)) + eps)
// One block = one 2048-wide output tile, everything via LDS prefix sums.
// ---------------------------------------------------------------------------
__global__ __launch_bounds__(256) void fused_kernel(const float* __restrict__ x,
                                                    const double* __restrict__ ws,
                                                    float* __restrict__ out,
                                                    long long n, int out_size) {
    __shared__ float lsz[SCAN_LEN];   // z prefix sums
    __shared__ float lsy[SCAN_LEN];   // y^2 prefix sums
    __shared__ float tsum[256];

    int tid = threadIdx.x;
    long long tile_start = (long long)blockIdx.x * TILE;

    // scalars (redundant per block; two cached 8B loads)
    double sum = ws[0], sumsq = ws[1];
    double mean = sum / (double)n;
    double var  = (sumsq - sum * mean) / (double)(n - 1);   // ddof=1
    float fmean = (float)mean;
    float finv  = (float)(1.0 / (sqrt(var) + 1e-5));

    // ---- load z (zero padding outside [0,n) reproduces jnp.pad) ----
    long long zbase = tile_start - PADZ;
    for (int j = tid; j < SCAN_LEN; j += 256) {
        float v = 0.f;
        long long g = zbase + j;
        if (j < TOTZ && g >= 0 && g < n) v = (x[g] - fmean) * finv;
        lsz[j] = v;
    }
    __syncthreads();
    scan_inplace(lsz, tsum, tid);          // lsz = inclusive prefix P of z

    // ---- y = z - windowsum251/251, squared, into lsy ----
    for (int jy = tid; jy < SCAN_LEN; jy += 256) {
        float yv = 0.f;
        if (jy < TOTY) {
            long long g = tile_start - PADY + jy;
            if (g >= 0 && g < n) {
                int jz = jy + (PADZ - PADY);              // +125, so jz-1 >= 124
                float zv = lsz[jz] - lsz[jz - 1];
                float lo = (jz - 126 >= 0) ? lsz[jz - 126] : 0.f;
                float wsum = lsz[jz + 125] - lo;
                yv = zv - wsum * (1.0f / 251.0f);
            }
        }
        lsy[jy] = yv * yv;
    }
    __syncthreads();
    scan_inplace(lsy, tsum, tid);          // lsy = inclusive prefix Q of y^2

    // ---- final output ----
    for (int o = tid; o < TILE; o += 256) {
        long long i = tile_start + o;
        if (i >= n) break;
        int jz = o + PADZ;                                 // >= 375
        float zv = lsz[jz] - lsz[jz - 1];
        float wsum = lsz[jz + 125] - lsz[jz - 126];
        float yv = zv - wsum * (1.0f / 251.0f);
        int jy = o + PADY;                                 // >= 250
        float qlo = (jy - 251 >= 0) ? lsy[jy - 251] : 0.f;
        float q = lsy[jy + 250] - qlo;
        float denom = sqrtf(q * (1.0f / 501.0f)) + EPS;
        out[i] = yv / denom;
    }

    // label passthrough (zeros) + any tail slots
    if (blockIdx.x == 0 && tid == 0) {
        for (long long k = n; k < (long long)out_size; ++k) out[k] = 0.f;
    }
}

// ---------------------------------------------------------------------------
extern "C" void kernel_launch(void* const* d_in, const int* in_sizes, int n_in,
                              void* d_out, int out_size, void* d_ws, size_t ws_size,
                              hipStream_t stream) {
    const float* x = (const float*)d_in[0];
    float* out     = (float*)d_out;
    double* ws     = (double*)d_ws;
    long long n    = (long long)in_sizes[0];

    // zero the two accumulator doubles (ws is re-poisoned to 0xAA each call)
    hipMemsetAsync(d_ws, 0, 2 * sizeof(double), stream);

    reduce_kernel<<<2048, 256, 0, stream>>>(x, n, ws);

    int nblocks = (int)((n + TILE - 1) / TILE);            // 8192 for N=16M
    fused_kernel<<<nblocks, 256, 0, stream>>>(x, ws, out, n, out_size);
}

// Round 2
// 197.335 us; speedup vs baseline: 1.0840x; 1.0840x over previous
//
#include <hip/hip_runtime.h>

// Problem constants
constexpr int   TILE   = 2048;          // outputs per block
constexpr int   PADZ   = 375;           // 125 (MA halo) + 250 (MV halo)
constexpr int   PADY   = 250;
constexpr int   TOTZ   = TILE + 2*PADZ; // 2798 z-values needed per block
constexpr int   TOTY   = TILE + 2*PADY; // 2548 y-values needed per block
constexpr int   PT     = 11;            // elems/thread in scan (coprime to 32 banks)
constexpr int   SCAN_LEN = 256 * PT;    // 2816 >= TOTZ
constexpr float EPS    = 1e-5f;

// ---------------------------------------------------------------------------
// Kernel 1: global sum / sum-of-squares reduction (double accumulation)
// ---------------------------------------------------------------------------
__global__ __launch_bounds__(256) void reduce_kernel(const float* __restrict__ x,
                                                     long long n, double* ws) {
    int tid = threadIdx.x;
    size_t gid    = (size_t)blockIdx.x * blockDim.x + tid;
    size_t stride = (size_t)gridDim.x * blockDim.x;
    double s = 0.0, s2 = 0.0;
    const float4* x4 = (const float4*)x;
    size_t n4 = (size_t)(n >> 2);
    for (size_t i = gid; i < n4; i += stride) {
        float4 v = x4[i];
        s  += (double)v.x + (double)v.y + (double)v.z + (double)v.w;
        s2 += (double)v.x * v.x + (double)v.y * v.y +
              (double)v.z * v.z + (double)v.w * v.w;
    }
    for (int off = 32; off; off >>= 1) {
        s  += __shfl_down(s, off);
        s2 += __shfl_down(s2, off);
    }
    __shared__ double ls[4], ls2[4];
    int wid = tid >> 6, lane = tid & 63;
    if (lane == 0) { ls[wid] = s; ls2[wid] = s2; }
    __syncthreads();
    if (tid == 0) {
        double a = 0.0, b = 0.0;
        for (int w = 0; w < 4; ++w) { a += ls[w]; b += ls2[w]; }
        atomicAdd(&ws[0], a);
        atomicAdd(&ws[1], b);
    }
}

// ---------------------------------------------------------------------------
// Kernel 2: fused z-score -> (z - MA251(z)) -> / (sqrt(MA501(y^2)) + eps)
// Register/shuffle scans: 6 barriers total per block (was ~40).
// ---------------------------------------------------------------------------
__global__ __launch_bounds__(256) void fused_kernel(const float* __restrict__ x,
                                                    const double* __restrict__ ws,
                                                    float* __restrict__ out,
                                                    long long n, int out_size) {
    __shared__ float ls[SCAN_LEN];   // prefix array (reused: P of z, then Q of y^2)
    __shared__ float ly[TILE];       // yv for the output range (coalesced epilogue)
    __shared__ float wtot[4];        // per-wave scan totals

    int tid  = threadIdx.x;
    int lane = tid & 63, wid = tid >> 6;
    long long tile_start = (long long)blockIdx.x * TILE;

    // scalars
    double sum = ws[0], sumsq = ws[1];
    double mean = sum / (double)n;
    double var  = (sumsq - sum * mean) / (double)(n - 1);   // ddof=1
    float fmean = (float)mean;
    float finv  = (float)(1.0 / (sqrt(var) + 1e-5));

    // ---- stage z into LDS, coalesced (zero padding outside [0,n)) ----
    long long zbase = tile_start - PADZ;
    for (int j = tid; j < SCAN_LEN; j += 256) {
        float v = 0.f;
        long long g = zbase + j;
        if (j < TOTZ && g >= 0 && g < n) v = (x[g] - fmean) * finv;
        ls[j] = v;
    }
    __syncthreads();                                   // (1)

    // ---- scan 1: inclusive prefix P of z ----
    const int base = tid * PT;
    float p[PT];
    float run = 0.f;
    #pragma unroll
    for (int k = 0; k < PT; ++k) { run += ls[base + k]; p[k] = run; }
    float incl = run;
    #pragma unroll
    for (int off = 1; off < 64; off <<= 1) {
        float v = __shfl_up(incl, off);
        if (lane >= off) incl += v;
    }
    if (lane == 63) wtot[wid] = incl;
    __syncthreads();                                   // (2)
    float excl = incl - run;
    for (int w = 0; w < wid; ++w) excl += wtot[w];
    #pragma unroll
    for (int k = 0; k < PT; ++k) ls[base + k] = p[k] + excl;
    __syncthreads();                                   // (3)

    // ---- y = z - windowsum251/251 (registers) + stash output range in ly ----
    float yv[PT];
    #pragma unroll
    for (int k = 0; k < PT; ++k) {
        int jy = base + k;
        float v = 0.f;
        if (jy < TOTY) {
            long long g = tile_start - PADY + jy;
            if (g >= 0 && g < n) {
                int jz = jy + (PADZ - PADY);           // +125
                float zv = ls[jz] - ls[jz - 1];
                float lo = (jz >= 126) ? ls[jz - 126] : 0.f;
                float wsum = ls[jz + 125] - lo;
                v = zv - wsum * (1.0f / 251.0f);
            }
        }
        yv[k] = v;
        int o = jy - PADY;
        if (o >= 0 && o < TILE) ly[o] = v;
    }
    __syncthreads();                                   // (4) P reads done

    // ---- scan 2: inclusive prefix Q of y^2 (overwrites ls in place) ----
    run = 0.f;
    #pragma unroll
    for (int k = 0; k < PT; ++k) { run += yv[k] * yv[k]; p[k] = run; }
    incl = run;
    #pragma unroll
    for (int off = 1; off < 64; off <<= 1) {
        float v = __shfl_up(incl, off);
        if (lane >= off) incl += v;
    }
    if (lane == 63) wtot[wid] = incl;
    __syncthreads();                                   // (5)
    excl = incl - run;
    for (int w = 0; w < wid; ++w) excl += wtot[w];
    #pragma unroll
    for (int k = 0; k < PT; ++k) ls[base + k] = p[k] + excl;
    __syncthreads();                                   // (6)

    // ---- coalesced epilogue ----
    for (int o = tid; o < TILE; o += 256) {
        long long i = tile_start + o;
        if (i >= n) break;
        int jy = o + PADY;
        float qlo = (o >= 1) ? ls[jy - 251] : 0.f;
        float q = ls[jy + 250] - qlo;
        float denom = sqrtf(q * (1.0f / 501.0f)) + EPS;
        out[i] = ly[o] / denom;
    }

    // label passthrough (zeros) + tail slots
    if (blockIdx.x == 0 && tid == 0) {
        for (long long k = n; k < (long long)out_size; ++k) out[k] = 0.f;
    }
}

// ---------------------------------------------------------------------------
extern "C" void kernel_launch(void* const* d_in, const int* in_sizes, int n_in,
                              void* d_out, int out_size, void* d_ws, size_t ws_size,
                              hipStream_t stream) {
    const float* x = (const float*)d_in[0];
    float* out     = (float*)d_out;
    double* ws     = (double*)d_ws;
    long long n    = (long long)in_sizes[0];

    hipMemsetAsync(d_ws, 0, 2 * sizeof(double), stream);

    reduce_kernel<<<2048, 256, 0, stream>>>(x, n, ws);

    int nblocks = (int)((n + TILE - 1) / TILE);        // 8192 for N=16M
    fused_kernel<<<nblocks, 256, 0, stream>>>(x, ws, out, n, out_size);
}

// Round 3
// 152.435 us; speedup vs baseline: 1.4032x; 1.2946x over previous
//
#include <hip/hip_runtime.h>

// Problem constants
constexpr int   TILE   = 2048;          // outputs per block
constexpr int   PADZ   = 375;           // 125 (MA halo) + 250 (MV halo)
constexpr int   PADY   = 250;
constexpr int   TOTZ   = TILE + 2*PADZ; // 2798 z-values needed per block
constexpr int   TOTY   = TILE + 2*PADY; // 2548 y-values needed per block
constexpr int   PT     = 11;            // elems/thread in scan (coprime to 32 banks)
constexpr int   SCAN_LEN = 256 * PT;    // 2816 >= TOTZ
constexpr float EPS    = 1e-5f;
constexpr int   RBLOCKS = 1024;         // reduce grid

// ---------------------------------------------------------------------------
// Kernel 1: per-block sum / sum-of-squares partials (NO atomics).
// 4 independent accumulator pairs + 4 batched loads per iter for MLP.
// ---------------------------------------------------------------------------
__global__ __launch_bounds__(256) void reduce_kernel(const float* __restrict__ x,
                                                     long long n,
                                                     double* __restrict__ partials) {
    int tid = threadIdx.x;
    size_t gid    = (size_t)blockIdx.x * 256 + tid;
    size_t stride = (size_t)RBLOCKS * 256;
    const float4* x4 = (const float4*)x;
    size_t n4 = (size_t)(n >> 2);

    double s0 = 0, s1 = 0, s2 = 0, s3 = 0;
    double q0 = 0, q1 = 0, q2 = 0, q3 = 0;
    size_t i = gid;
    for (; i + 3 * stride < n4; i += 4 * stride) {
        float4 v0 = x4[i];
        float4 v1 = x4[i + stride];
        float4 v2 = x4[i + 2 * stride];
        float4 v3 = x4[i + 3 * stride];
        s0 += (double)v0.x + (double)v0.y + (double)v0.z + (double)v0.w;
        q0 += (double)v0.x * v0.x + (double)v0.y * v0.y + (double)v0.z * v0.z + (double)v0.w * v0.w;
        s1 += (double)v1.x + (double)v1.y + (double)v1.z + (double)v1.w;
        q1 += (double)v1.x * v1.x + (double)v1.y * v1.y + (double)v1.z * v1.z + (double)v1.w * v1.w;
        s2 += (double)v2.x + (double)v2.y + (double)v2.z + (double)v2.w;
        q2 += (double)v2.x * v2.x + (double)v2.y * v2.y + (double)v2.z * v2.z + (double)v2.w * v2.w;
        s3 += (double)v3.x + (double)v3.y + (double)v3.z + (double)v3.w;
        q3 += (double)v3.x * v3.x + (double)v3.y * v3.y + (double)v3.z * v3.z + (double)v3.w * v3.w;
    }
    for (; i < n4; i += stride) {
        float4 v = x4[i];
        s0 += (double)v.x + (double)v.y + (double)v.z + (double)v.w;
        q0 += (double)v.x * v.x + (double)v.y * v.y + (double)v.z * v.z + (double)v.w * v.w;
    }
    double s = (s0 + s1) + (s2 + s3);
    double q = (q0 + q1) + (q2 + q3);

    for (int off = 32; off; off >>= 1) {
        s += __shfl_down(s, off);
        q += __shfl_down(q, off);
    }
    __shared__ double ls[4], lq[4];
    int wid = tid >> 6, lane = tid & 63;
    if (lane == 0) { ls[wid] = s; lq[wid] = q; }
    __syncthreads();
    if (tid == 0) {
        double a = 0, b = 0;
        for (int w = 0; w < 4; ++w) { a += ls[w]; b += lq[w]; }
        partials[2 * blockIdx.x]     = a;
        partials[2 * blockIdx.x + 1] = b;
    }
}

// ---------------------------------------------------------------------------
// Kernel 1b: combine 1024 partial pairs -> ws[0]=sum, ws[1]=sumsq
// ---------------------------------------------------------------------------
__global__ __launch_bounds__(256) void combine_kernel(const double* __restrict__ partials,
                                                      double* __restrict__ ws) {
    int tid = threadIdx.x;
    double s = 0, q = 0;
    for (int i = tid; i < RBLOCKS; i += 256) {
        s += partials[2 * i];
        q += partials[2 * i + 1];
    }
    for (int off = 32; off; off >>= 1) {
        s += __shfl_down(s, off);
        q += __shfl_down(q, off);
    }
    __shared__ double ls[4], lq[4];
    int wid = tid >> 6, lane = tid & 63;
    if (lane == 0) { ls[wid] = s; lq[wid] = q; }
    __syncthreads();
    if (tid == 0) {
        double a = 0, b = 0;
        for (int w = 0; w < 4; ++w) { a += ls[w]; b += lq[w]; }
        ws[0] = a;
        ws[1] = b;
    }
}

// ---------------------------------------------------------------------------
// Kernel 2: fused z-score -> (z - MA251(z)) -> / (sqrt(MA501(y^2)) + eps)
// Register/shuffle scans: 6 barriers per block. (unchanged from R2)
// ---------------------------------------------------------------------------
__global__ __launch_bounds__(256) void fused_kernel(const float* __restrict__ x,
                                                    const double* __restrict__ ws,
                                                    float* __restrict__ out,
                                                    long long n, int out_size) {
    __shared__ float ls[SCAN_LEN];   // prefix array (reused: P of z, then Q of y^2)
    __shared__ float ly[TILE];       // yv for the output range (coalesced epilogue)
    __shared__ float wtot[4];        // per-wave scan totals

    int tid  = threadIdx.x;
    int lane = tid & 63, wid = tid >> 6;
    long long tile_start = (long long)blockIdx.x * TILE;

    // scalars
    double sum = ws[0], sumsq = ws[1];
    double mean = sum / (double)n;
    double var  = (sumsq - sum * mean) / (double)(n - 1);   // ddof=1
    float fmean = (float)mean;
    float finv  = (float)(1.0 / (sqrt(var) + 1e-5));

    // ---- stage z into LDS, coalesced (zero padding outside [0,n)) ----
    long long zbase = tile_start - PADZ;
    for (int j = tid; j < SCAN_LEN; j += 256) {
        float v = 0.f;
        long long g = zbase + j;
        if (j < TOTZ && g >= 0 && g < n) v = (x[g] - fmean) * finv;
        ls[j] = v;
    }
    __syncthreads();                                   // (1)

    // ---- scan 1: inclusive prefix P of z ----
    const int base = tid * PT;
    float p[PT];
    float run = 0.f;
    #pragma unroll
    for (int k = 0; k < PT; ++k) { run += ls[base + k]; p[k] = run; }
    float incl = run;
    #pragma unroll
    for (int off = 1; off < 64; off <<= 1) {
        float v = __shfl_up(incl, off);
        if (lane >= off) incl += v;
    }
    if (lane == 63) wtot[wid] = incl;
    __syncthreads();                                   // (2)
    float excl = incl - run;
    for (int w = 0; w < wid; ++w) excl += wtot[w];
    #pragma unroll
    for (int k = 0; k < PT; ++k) ls[base + k] = p[k] + excl;
    __syncthreads();                                   // (3)

    // ---- y = z - windowsum251/251 (registers) + stash output range in ly ----
    float yv[PT];
    #pragma unroll
    for (int k = 0; k < PT; ++k) {
        int jy = base + k;
        float v = 0.f;
        if (jy < TOTY) {
            long long g = tile_start - PADY + jy;
            if (g >= 0 && g < n) {
                int jz = jy + (PADZ - PADY);           // +125
                float zv = ls[jz] - ls[jz - 1];
                float lo = (jz >= 126) ? ls[jz - 126] : 0.f;
                float wsum = ls[jz + 125] - lo;
                v = zv - wsum * (1.0f / 251.0f);
            }
        }
        yv[k] = v;
        int o = jy - PADY;
        if (o >= 0 && o < TILE) ly[o] = v;
    }
    __syncthreads();                                   // (4) P reads done

    // ---- scan 2: inclusive prefix Q of y^2 (overwrites ls in place) ----
    run = 0.f;
    #pragma unroll
    for (int k = 0; k < PT; ++k) { run += yv[k] * yv[k]; p[k] = run; }
    incl = run;
    #pragma unroll
    for (int off = 1; off < 64; off <<= 1) {
        float v = __shfl_up(incl, off);
        if (lane >= off) incl += v;
    }
    if (lane == 63) wtot[wid] = incl;
    __syncthreads();                                   // (5)
    excl = incl - run;
    for (int w = 0; w < wid; ++w) excl += wtot[w];
    #pragma unroll
    for (int k = 0; k < PT; ++k) ls[base + k] = p[k] + excl;
    __syncthreads();                                   // (6)

    // ---- coalesced epilogue ----
    for (int o = tid; o < TILE; o += 256) {
        long long i = tile_start + o;
        if (i >= n) break;
        int jy = o + PADY;
        float qlo = (o >= 1) ? ls[jy - 251] : 0.f;
        float q = ls[jy + 250] - qlo;
        float denom = sqrtf(q * (1.0f / 501.0f)) + EPS;
        out[i] = ly[o] / denom;
    }

    // label passthrough (zeros) + tail slots
    if (blockIdx.x == 0 && tid == 0) {
        for (long long k = n; k < (long long)out_size; ++k) out[k] = 0.f;
    }
}

// ---------------------------------------------------------------------------
extern "C" void kernel_launch(void* const* d_in, const int* in_sizes, int n_in,
                              void* d_out, int out_size, void* d_ws, size_t ws_size,
                              hipStream_t stream) {
    const float* x = (const float*)d_in[0];
    float* out     = (float*)d_out;
    double* ws     = (double*)d_ws;            // ws[0..1] = sum, sumsq
    double* partials = ws + 2;                 // 2*RBLOCKS doubles (16 KB)
    long long n    = (long long)in_sizes[0];

    reduce_kernel<<<RBLOCKS, 256, 0, stream>>>(x, n, partials);
    combine_kernel<<<1, 256, 0, stream>>>(partials, ws);

    int nblocks = (int)((n + TILE - 1) / TILE);        // 8192 for N=16M
    fused_kernel<<<nblocks, 256, 0, stream>>>(x, ws, out, n, out_size);
}

// Round 4
// 139.247 us; speedup vs baseline: 1.5361x; 1.0947x over previous
//
#include <hip/hip_runtime.h>

// Problem constants
constexpr int   TILE  = 2048;          // outputs per block
constexpr int   PT    = 12;            // scan1 chunk: 48B/thread, 16B-aligned
constexpr int   PT2   = 10;            // scan2 chunk (256*10=2560 >= TOTY)
constexpr int   TOTZ  = 2800;          // z elements staged: [g0, g0+2800), g0 = tile_start-376
constexpr int   TOTY  = TILE + 500;    // 2548 y values
constexpr int   LS_CAP = 2804;         // P/Q array floats (needs 2800 / 2561)
constexpr int   SCAN_SPAN = 256 * PT;  // 3072: scan1 chunk-read span
constexpr int   NLDS  = LS_CAP + TILE + 8;   // ls + ly + wtot, single buffer
constexpr float EPS   = 1e-5f;
constexpr float R251  = 1.0f / 251.0f;
constexpr float R501  = 1.0f / 501.0f;
constexpr int   RBLOCKS = 1024;

// ---------------------------------------------------------------------------
// Kernel 1: per-block sum / sumsq partials. f32 inner accumulation (chains of
// length 4), f64 only once per float4 -> 8x less f64 VALU than before.
// ---------------------------------------------------------------------------
__global__ __launch_bounds__(256) void reduce_kernel(const float* __restrict__ x,
                                                     int n,
                                                     double* __restrict__ partials) {
    int tid = threadIdx.x;
    int gid = blockIdx.x * 256 + tid;
    const int stride = RBLOCKS * 256;
    const float4* x4 = (const float4*)x;
    int n4 = n >> 2;

    double s = 0.0, q = 0.0;
    #pragma unroll 4
    for (int i = gid; i < n4; i += stride) {
        float4 v = x4[i];
        float sf = (v.x + v.y) + (v.z + v.w);
        float qf = fmaf(v.x, v.x, fmaf(v.y, v.y, fmaf(v.z, v.z, v.w * v.w)));
        s += (double)sf;
        q += (double)qf;
    }
    for (int off = 32; off; off >>= 1) {
        s += __shfl_down(s, off);
        q += __shfl_down(q, off);
    }
    __shared__ double ls_[4], lq_[4];
    int wid = tid >> 6, lane = tid & 63;
    if (lane == 0) { ls_[wid] = s; lq_[wid] = q; }
    __syncthreads();
    if (tid == 0) {
        double a = 0, b = 0;
        for (int w = 0; w < 4; ++w) { a += ls_[w]; b += lq_[w]; }
        partials[2 * blockIdx.x]     = a;
        partials[2 * blockIdx.x + 1] = b;
    }
}

// ---------------------------------------------------------------------------
// Kernel 1b: combine partials -> ws[0]=sum, ws[1]=sumsq
// ---------------------------------------------------------------------------
__global__ __launch_bounds__(256) void combine_kernel(const double* __restrict__ partials,
                                                      double* __restrict__ ws) {
    int tid = threadIdx.x;
    double s = 0, q = 0;
    for (int i = tid; i < RBLOCKS; i += 256) {
        s += partials[2 * i];
        q += partials[2 * i + 1];
    }
    for (int off = 32; off; off >>= 1) {
        s += __shfl_down(s, off);
        q += __shfl_down(q, off);
    }
    __shared__ double ls_[4], lq_[4];
    int wid = tid >> 6, lane = tid & 63;
    if (lane == 0) { ls_[wid] = s; lq_[wid] = q; }
    __syncthreads();
    if (tid == 0) {
        double a = 0, b = 0;
        for (int w = 0; w < 4; ++w) { a += ls_[w]; b += lq_[w]; }
        ws[0] = a;
        ws[1] = b;
    }
}

// ---------------------------------------------------------------------------
// Kernel 2: fused z-score -> (z - MA251) -> / (sqrt(MA501(y^2)) + eps).
// Interior blocks (8190 of 8192): vectorized, zero per-element bounds checks.
// LDS layout: ls[0..2804) = z then P then Q(+1 shift); ly[0..2048) = yv.
// ---------------------------------------------------------------------------
__global__ __launch_bounds__(256) void fused_kernel(const float* __restrict__ x,
                                                    const double* __restrict__ ws,
                                                    float* __restrict__ out,
                                                    int n, int out_size) {
    __shared__ __align__(16) float lds_all[NLDS];
    float* ls   = lds_all;               // byte 0, 16B-aligned
    float* ly   = lds_all + LS_CAP;      // byte 11216, 16B-aligned
    float* wtot = lds_all + LS_CAP + TILE;

    const int tid  = threadIdx.x;
    const int lane = tid & 63, wid = tid >> 6;
    const int tile_start = blockIdx.x * TILE;
    const int g0 = tile_start - 376;     // multiple of 4
    const bool fast = (g0 >= 0) && (g0 + TOTZ <= n);

    // scalars
    double sum = ws[0], sumsq = ws[1];
    double mean = sum / (double)n;
    double var  = (sumsq - sum * mean) / (double)(n - 1);   // ddof=1
    double invd = 1.0 / (sqrt(var) + 1e-5);
    const float finv = (float)invd;
    const float nmf  = (float)(-mean * invd);               // z = fma(x, finv, nmf)

    // ---- stage z into LDS ----
    if (fast) {
        const float4* x4 = (const float4*)x + (g0 >> 2);
        for (int f = tid; f < TOTZ / 4; f += 256) {          // 700 float4s
            float4 v = x4[f];
            v.x = fmaf(v.x, finv, nmf);
            v.y = fmaf(v.y, finv, nmf);
            v.z = fmaf(v.z, finv, nmf);
            v.w = fmaf(v.w, finv, nmf);
            ((float4*)ls)[f] = v;
        }
        for (int j = TOTZ + tid; j < LS_CAP; j += 256) ls[j] = 0.f;
    } else {
        for (int j = tid; j < LS_CAP; j += 256) {
            int g = g0 + j;
            float v = 0.f;
            if (j < TOTZ && (unsigned)g < (unsigned)n) v = fmaf(x[g], finv, nmf);
            ls[j] = v;
        }
    }
    // zero the scan over-read region [LS_CAP, SCAN_SPAN) (lands in ly; ly is
    // rewritten later). Guarantees clean chunk sums for threads >= 233.
    for (int j = LS_CAP + tid; j < SCAN_SPAN; j += 256) lds_all[j] = 0.f;
    __syncthreads();                                   // (1)

    // ---- scan 1: inclusive prefix P of z (vector LDS chunk I/O) ----
    const int base = tid * PT;                         // 48B-aligned
    float p[PT];
    {
        const float4* lsv = (const float4*)ls + (base >> 2);
        float4 a0 = lsv[0], a1 = lsv[1], a2 = lsv[2];
        float run = 0.f;
        p[0]  = run += a0.x;  p[1]  = run += a0.y;
        p[2]  = run += a0.z;  p[3]  = run += a0.w;
        p[4]  = run += a1.x;  p[5]  = run += a1.y;
        p[6]  = run += a1.z;  p[7]  = run += a1.w;
        p[8]  = run += a2.x;  p[9]  = run += a2.y;
        p[10] = run += a2.z;  p[11] = run += a2.w;
        float incl = run;
        #pragma unroll
        for (int off = 1; off < 64; off <<= 1) {
            float v = __shfl_up(incl, off);
            if (lane >= off) incl += v;
        }
        if (lane == 63) wtot[wid] = incl;
        __syncthreads();                               // (2)
        float excl = incl - run;
        float t0 = wtot[0], t1 = wtot[1], t2 = wtot[2];
        if (wid > 0) excl += t0;
        if (wid > 1) excl += t1;
        if (wid > 2) excl += t2;
        #pragma unroll
        for (int k = 0; k < PT; ++k) p[k] += excl;
        if (base + PT <= TOTZ) {
            float4* wv = (float4*)ls + (base >> 2);
            wv[0] = make_float4(p[0], p[1], p[2],  p[3]);
            wv[1] = make_float4(p[4], p[5], p[6],  p[7]);
            wv[2] = make_float4(p[8], p[9], p[10], p[11]);
        } else {
            #pragma unroll
            for (int k = 0; k < PT; ++k)
                if (base + k < TOTZ) ls[base + k] = p[k];
        }
    }
    __syncthreads();                                   // (3)

    // ---- y = z - windowsum251/251 at jy in [b2, b2+10) ----
    const int b2 = tid * PT2;
    float yv[PT2];
    if (fast) {
        #pragma unroll
        for (int k = 0; k < PT2; ++k) {
            int jy = b2 + k;
            float v = 0.f;
            if (jy < TOTY) {
                int jz = jy + 126;
                float zv = ls[jz] - ls[jz - 1];
                float wsum = ls[jz + 125] - ls[jz - 126];
                v = fmaf(wsum, -R251, zv);
            }
            yv[k] = v;
        }
    } else {
        #pragma unroll
        for (int k = 0; k < PT2; ++k) {
            int jy = b2 + k;
            float v = 0.f;
            int gy = tile_start - 250 + jy;
            if (jy < TOTY && (unsigned)gy < (unsigned)n) {
                int jz = jy + 126;
                float zv = ls[jz] - ls[jz - 1];
                float wsum = ls[jz + 125] - ls[jz - 126];
                v = fmaf(wsum, -R251, zv);
            }
            yv[k] = v;
        }
    }
    #pragma unroll
    for (int k = 0; k < PT2; ++k) {
        int o = b2 + k - 250;
        if ((unsigned)o < (unsigned)TILE) ly[o] = yv[k];
    }
    __syncthreads();                                   // (4) P reads done

    // ---- scan 2: prefix Q of y^2, stored at ls[j+1] (ls[0] = Q[-1] = 0) ----
    {
        float q[PT2];
        float run = 0.f;
        #pragma unroll
        for (int k = 0; k < PT2; ++k) { run = fmaf(yv[k], yv[k], run); q[k] = run; }
        float incl = run;
        #pragma unroll
        for (int off = 1; off < 64; off <<= 1) {
            float v = __shfl_up(incl, off);
            if (lane >= off) incl += v;
        }
        if (lane == 63) wtot[wid] = incl;
        __syncthreads();                               // (5)
        float excl = incl - run;
        float t0 = wtot[0], t1 = wtot[1], t2 = wtot[2];
        if (wid > 0) excl += t0;
        if (wid > 1) excl += t1;
        if (wid > 2) excl += t2;
        #pragma unroll
        for (int k = 0; k < PT2; ++k) ls[1 + b2 + k] = q[k] + excl;
        if (tid == 0) ls[0] = 0.f;
    }
    __syncthreads();                                   // (6)

    // ---- vectorized epilogue: q = ls[o+501] - ls[o] ----
    for (int t = tid; t < TILE / 4; t += 256) {        // 2 iterations
        int o = t * 4;
        int i = tile_start + o;
        float4 yl  = *((const float4*)(ly + o));
        float4 ql  = *((const float4*)(ls + o));
        float qh0 = ls[o + 501], qh1 = ls[o + 502];
        float qh2 = ls[o + 503], qh3 = ls[o + 504];
        float4 r;
        r.x = yl.x * __builtin_amdgcn_rcpf(__builtin_amdgcn_sqrtf((qh0 - ql.x) * R501) + EPS);
        r.y = yl.y * __builtin_amdgcn_rcpf(__builtin_amdgcn_sqrtf((qh1 - ql.y) * R501) + EPS);
        r.z = yl.z * __builtin_amdgcn_rcpf(__builtin_amdgcn_sqrtf((qh2 - ql.z) * R501) + EPS);
        r.w = yl.w * __builtin_amdgcn_rcpf(__builtin_amdgcn_sqrtf((qh3 - ql.w) * R501) + EPS);
        if (i + 3 < n) {
            ((float4*)out)[(tile_start >> 2) + t] = r;
        } else {
            if (i     < n) out[i]     = r.x;
            if (i + 1 < n) out[i + 1] = r.y;
            if (i + 2 < n) out[i + 2] = r.z;
            if (i + 3 < n) out[i + 3] = r.w;
        }
    }

    // label passthrough (zeros) + tail slots
    if (blockIdx.x == 0 && tid == 0) {
        for (int k = n; k < out_size; ++k) out[k] = 0.f;
    }
}

// ---------------------------------------------------------------------------
extern "C" void kernel_launch(void* const* d_in, const int* in_sizes, int n_in,
                              void* d_out, int out_size, void* d_ws, size_t ws_size,
                              hipStream_t stream) {
    const float* x = (const float*)d_in[0];
    float* out     = (float*)d_out;
    double* ws     = (double*)d_ws;            // ws[0..1] = sum, sumsq
    double* partials = ws + 2;                 // 2*RBLOCKS doubles (16 KB)
    int n = in_sizes[0];

    reduce_kernel<<<RBLOCKS, 256, 0, stream>>>(x, n, partials);
    combine_kernel<<<1, 256, 0, stream>>>(partials, ws);

    int nblocks = (n + TILE - 1) / TILE;       // 8192 for N=16M
    fused_kernel<<<nblocks, 256, 0, stream>>>(x, ws, out, n, out_size);
}